// Round 1
// baseline (676.567 us; speedup 1.0000x reference)
//
#include <hip/hip_runtime.h>

#define Bq 8
#define Sq 256
#define Hq 100
#define Pq 20
#define Fq 105
#define EPSq 1e-8f

// ---------------- k_len: per-batch mask sums + last valid index ----------------
__global__ __launch_bounds__(256) void k_len(const int* __restrict__ mp, const int* __restrict__ mh,
                                             float* lenp, float* lenh, int* lastp, int* lasth) {
    __shared__ int sp[256], sh[256];
    int b = blockIdx.x, t = threadIdx.x;
    sp[t] = mp[b * Sq + t];
    sh[t] = mh[b * Sq + t];
    __syncthreads();
    for (int o = 128; o > 0; o >>= 1) {
        if (t < o) { sp[t] += sp[t + o]; sh[t] += sh[t + o]; }
        __syncthreads();
    }
    if (t == 0) {
        int lp = sp[0], lh2 = sh[0];
        lenp[b] = (float)lp;
        lenh[b] = (float)lh2;
        lastp[b] = lp > 0 ? lp - 1 : 0;
        lasth[b] = lh2 > 0 ? lh2 - 1 : 0;
    }
}

// ---------------- k_prep: masked vectors, raw norms, maxpool-weighted norms ----------------
// grid = 2*B*S blocks of 64 (one wave per token; side 0 = premise, 1 = hypothesis)
__global__ __launch_bounds__(64) void k_prep(
    const float* __restrict__ ctx_p, const int* __restrict__ mask_p,
    const float* __restrict__ ctx_h, const int* __restrict__ mask_h,
    const float* __restrict__ w_mp,
    float* __restrict__ vm /* cp_m | ch_m */, float* __restrict__ norms /* normp | normh */,
    float* __restrict__ nw /* n1w | n2w */) {
    int blk = blockIdx.x;
    int side = blk / (Bq * Sq);
    int rem = blk - side * (Bq * Sq);
    int b = rem / Sq, s = rem - b * Sq;
    int lane = threadIdx.x;
    const float* ctx = side ? ctx_h : ctx_p;
    const int* mask = side ? mask_h : mask_p;
    float* vout = vm + (size_t)side * Bq * Sq * Hq;
    float* nout = norms + side * Bq * Sq;
    float* nwout = nw + (size_t)side * Bq * Pq * Sq;

    float m = (float)mask[b * Sq + s];
    const float* v = ctx + ((size_t)b * Sq + s) * Hq;
    float v1 = v[lane] * m;                                   // lane < 64 < 100 always valid
    float v2 = (lane + 64 < Hq) ? v[lane + 64] * m : 0.f;
    float* vo = vout + ((size_t)b * Sq + s) * Hq;
    vo[lane] = v1;
    if (lane + 64 < Hq) vo[lane + 64] = v2;

    float ss = v1 * v1 + v2 * v2;
    for (int o = 32; o; o >>= 1) ss += __shfl_xor(ss, o, 64);
    if (lane == 0) nout[b * Sq + s] = sqrtf(ss);

    for (int p = 0; p < Pq; p++) {
        float wa = w_mp[p * Hq + lane];
        float wb = (lane + 64 < Hq) ? w_mp[p * Hq + lane + 64] : 0.f;
        float t1 = wa * v1, t2 = wb * v2;
        float s2 = t1 * t1 + t2 * t2;
        for (int o = 32; o; o >>= 1) s2 += __shfl_xor(s2, o, 64);
        if (lane == 0) nwout[((size_t)b * Pq + p) * Sq + s] = sqrtf(s2);
    }
}

// ---------------- k_main: per (b,i) row — cos row, row stats, attention vecs, pw stats ----------
// Launched once per direction with swapped operands. block=256, grid=B*S.
__global__ __launch_bounds__(256) void k_main(
    const float* __restrict__ A, const float* __restrict__ O, const int* __restrict__ mO,
    const float* __restrict__ normA, const float* __restrict__ normO,
    const float* __restrict__ nwA, const float* __restrict__ nwO,
    const float* __restrict__ lenO, const float* __restrict__ w_mp,
    float* __restrict__ attmean, float* __restrict__ attmax,
    float* __restrict__ out, int obase) {
    __shared__ float os[Sq * Hq];        // 100 KB: all other-side vectors for this batch
    __shared__ float mos[Sq];
    __shared__ float ai[Hq];
    __shared__ float cosr[Sq];
    __shared__ float wcpa[Pq * Hq];      // w_p^2 * ai, all perspectives
    __shared__ float red[16];

    int b = blockIdx.x / Sq, i = blockIdx.x - (blockIdx.x / Sq) * Sq;
    int t = threadIdx.x, lid = t & 63, wid = t >> 6;

    // stage other side (Sq*Hq floats = 6400 float4)
    const float4* Ob = (const float4*)(O + (size_t)b * Sq * Hq);
    float4* os4 = (float4*)os;
#pragma unroll
    for (int k = 0; k < 25; k++) os4[t + 256 * k] = Ob[t + 256 * k];
    mos[t] = (float)mO[b * Sq + t];
    if (t < 25) ((float4*)ai)[t] = ((const float4*)(A + ((size_t)b * Sq + i) * Hq))[t];
    __syncthreads();

    // cos row: thread t handles j = t
    float nAi = fmaxf(normA[b * Sq + i], EPSq);
    float nOj = fmaxf(normO[b * Sq + t], EPSq);
    const float4* ojp = (const float4*)(os + t * Hq);
    float d = 0.f;
#pragma unroll
    for (int k = 0; k < 25; k++) {
        float4 o4 = ojp[k];
        float4 a4 = ((const float4*)ai)[k];
        d += o4.x * a4.x + o4.y * a4.y + o4.z * a4.z + o4.w * a4.w;
    }
    float c = d / (nAi * nOj);
    cosr[t] = c;
    float mj = mos[t];
    float vmax = mj > 0.5f ? c : -1e30f;
    float vsum = c;
    for (int o = 32; o; o >>= 1) {
        vmax = fmaxf(vmax, __shfl_xor(vmax, o, 64));
        vsum += __shfl_xor(vsum, o, 64);
    }
    if (lid == 0) { red[wid] = vmax; red[4 + wid] = vsum; }
    __syncthreads();

    float rowsum = red[4] + red[5] + red[6] + red[7];
    float lh = lenO[b];
    float* orow = out + obase + ((size_t)b * Sq + i) * Fq;
    if (t == 0) {
        float rowmax = fmaxf(fmaxf(red[0], red[1]), fmaxf(red[2], red[3]));
        orow[0] = rowmax;                              // cos masked max
        orow[1] = rowsum / fmaxf(lh, EPSq);            // cos masked mean
    }

    // precompute wcpa[p][h] = w^2 * ai[h]
    for (int idx = t; idx < Pq * Hq; idx += 256) {
        int p = idx / Hq, h = idx - p * Hq;
        float w = w_mp[idx];
        (void)p;
        wcpa[idx] = w * w * ai[h];
    }

    // attention mean / masked-max vectors (threads 0..99, one h each)
    float denom = fmaxf(rowsum, EPSq);
    if (t < Hq) {
        float sacc = 0.f, macc = -1e30f;
        for (int j = 0; j < Sq; j++) {
            float cj = cosr[j];
            float v = os[j * Hq + t];
            float pr = cj * v;
            sacc += pr;
            macc = (mos[j] > 0.5f) ? fmaxf(macc, pr) : macc;
        }
        attmean[((size_t)b * Sq + i) * Hq + t] = sacc / denom;
        attmax[((size_t)b * Sq + i) * Hq + t] = macc;
    }
    __syncthreads();   // wcpa ready

    // pairwise multi-perspective: thread t = j, 20 accumulators, 1 ch read feeds 20 FMAs*4
    float acc[Pq];
#pragma unroll
    for (int p = 0; p < Pq; p++) acc[p] = 0.f;
    const float4* wk = (const float4*)wcpa;
#pragma unroll 5
    for (int k = 0; k < 25; k++) {
        float4 o4 = ojp[k];
#pragma unroll
        for (int p = 0; p < Pq; p++) {
            float4 w4 = wk[p * 25 + k];
            acc[p] += w4.x * o4.x + w4.y * o4.y + w4.z * o4.z + w4.w * o4.w;
        }
    }
    for (int p = 0; p < Pq; p++) {
        float n1p = nwA[((size_t)b * Pq + p) * Sq + i];
        float n2p = nwO[((size_t)b * Pq + p) * Sq + t];
        float pwv = acc[p] / fmaxf(n1p * n2p, EPSq);
        float pmax = mj > 0.5f ? pwv : -1e30f;
        float psum = pwv;
        for (int o = 32; o; o >>= 1) {
            pmax = fmaxf(pmax, __shfl_xor(pmax, o, 64));
            psum += __shfl_xor(psum, o, 64);
        }
        __syncthreads();
        if (lid == 0) { red[wid] = pmax; red[8 + wid] = psum; }
        __syncthreads();
        if (t == 0) {
            orow[23 + p] = fmaxf(fmaxf(red[0], red[1]), fmaxf(red[2], red[3]));
            orow[43 + p] = (red[8] + red[9] + red[10] + red[11]) / fmaxf(lh, EPSq);
        }
    }
}

// ---------------- k_final: the three _mpm blocks (full / attentive / max-attentive) -----------
__device__ __forceinline__ void mpm_pair(float v1a, float v1b, const float* __restrict__ v2,
                                         const float* __restrict__ W, int lane,
                                         float* __restrict__ orow, int fbase) {
    float v2a = v2[lane];
    float v2b = (lane + 64 < Hq) ? v2[lane + 64] : 0.f;
    float d = v1a * v2a + v1b * v2b;
    float n1 = v1a * v1a + v1b * v1b;
    float n2 = v2a * v2a + v2b * v2b;
    for (int o = 32; o; o >>= 1) {
        d += __shfl_xor(d, o, 64);
        n1 += __shfl_xor(n1, o, 64);
        n2 += __shfl_xor(n2, o, 64);
    }
    if (lane == 0) orow[fbase] = d / (fmaxf(sqrtf(n1), EPSq) * fmaxf(sqrtf(n2), EPSq));
    for (int p = 0; p < Pq; p++) {
        float wa = W[p * Hq + lane];
        float wb = (lane + 64 < Hq) ? W[p * Hq + lane + 64] : 0.f;
        float x1 = wa * v1a, y1 = wb * v1b, x2 = wa * v2a, y2 = wb * v2b;
        float dd = x1 * x2 + y1 * y2;
        float m1 = x1 * x1 + y1 * y1;
        float m2 = x2 * x2 + y2 * y2;
        for (int o = 32; o; o >>= 1) {
            dd += __shfl_xor(dd, o, 64);
            m1 += __shfl_xor(m1, o, 64);
            m2 += __shfl_xor(m2, o, 64);
        }
        if (lane == 0) orow[fbase + 1 + p] = dd / (fmaxf(sqrtf(m1), EPSq) * fmaxf(sqrtf(m2), EPSq));
    }
}

__global__ __launch_bounds__(64) void k_final(
    const float* __restrict__ vm,
    const int* __restrict__ lastp, const int* __restrict__ lasth,
    const float* __restrict__ amh, const float* __restrict__ amp,
    const float* __restrict__ axh, const float* __restrict__ axp,
    const float* __restrict__ w_full, const float* __restrict__ w_att,
    const float* __restrict__ w_maxatt,
    float* __restrict__ out) {
    int blk = blockIdx.x;
    int dir = blk / (Bq * Sq);
    int rem = blk - dir * (Bq * Sq);
    int b = rem / Sq, s = rem - b * Sq;
    int lane = threadIdx.x;
    const float* A = vm + (size_t)dir * Bq * Sq * Hq;
    const float* Ov = vm + (size_t)(1 - dir) * Bq * Sq * Hq;
    int lastO = dir ? lastp[b] : lasth[b];
    const float* v1 = A + ((size_t)b * Sq + s) * Hq;
    const float* v2full = Ov + ((size_t)b * Sq + lastO) * Hq;
    const float* v2att = (dir ? amp : amh) + ((size_t)b * Sq + s) * Hq;
    const float* v2max = (dir ? axp : axh) + ((size_t)b * Sq + s) * Hq;
    float v1a = v1[lane];
    float v1b = (lane + 64 < Hq) ? v1[lane + 64] : 0.f;
    float* orow = out + (size_t)dir * Bq * Sq * Fq + ((size_t)b * Sq + s) * Fq;
    mpm_pair(v1a, v1b, v2full, w_full, lane, orow, 2);
    mpm_pair(v1a, v1b, v2att, w_att, lane, orow, 63);
    mpm_pair(v1a, v1b, v2max, w_maxatt, lane, orow, 84);
}

extern "C" void kernel_launch(void* const* d_in, const int* in_sizes, int n_in,
                              void* d_out, int out_size, void* d_ws, size_t ws_size,
                              hipStream_t stream) {
    (void)in_sizes; (void)n_in; (void)out_size; (void)ws_size;
    const float* ctx_p   = (const float*)d_in[0];
    const int*   mask_p  = (const int*)d_in[1];
    const float* ctx_h   = (const float*)d_in[2];
    const int*   mask_h  = (const int*)d_in[3];
    const float* w_full  = (const float*)d_in[4];
    const float* w_maxpool = (const float*)d_in[5];
    const float* w_att   = (const float*)d_in[6];
    const float* w_maxatt = (const float*)d_in[7];
    float* out = (float*)d_out;
    float* ws = (float*)d_ws;

    const size_t BSH = (size_t)Bq * Sq * Hq;   // 204800
    const size_t BS  = (size_t)Bq * Sq;        // 2048
    const size_t BPS = (size_t)Bq * Pq * Sq;   // 40960
    float* cp_m  = ws;
    float* ch_m  = cp_m + BSH;
    float* normp = ch_m + BSH;
    float* normh = normp + BS;
    float* n1w   = normh + BS;
    float* n2w   = n1w + BPS;
    float* amh   = n2w + BPS;
    float* amp   = amh + BSH;
    float* axh   = amp + BSH;
    float* axp   = axh + BSH;
    float* lenp  = axp + BSH;
    float* lenh  = lenp + Bq;
    int*   lastp = (int*)(lenh + Bq);
    int*   lasth = lastp + Bq;

    k_len<<<Bq, 256, 0, stream>>>(mask_p, mask_h, lenp, lenh, lastp, lasth);
    k_prep<<<2 * Bq * Sq, 64, 0, stream>>>(ctx_p, mask_p, ctx_h, mask_h, w_maxpool,
                                           cp_m, normp, n1w);
    k_main<<<Bq * Sq, 256, 0, stream>>>(cp_m, ch_m, mask_h, normp, normh, n1w, n2w,
                                        lenh, w_maxpool, amh, axh, out, 0);
    k_main<<<Bq * Sq, 256, 0, stream>>>(ch_m, cp_m, mask_p, normh, normp, n2w, n1w,
                                        lenp, w_maxpool, amp, axp, out, Bq * Sq * Fq);
    k_final<<<2 * Bq * Sq, 64, 0, stream>>>(cp_m, lastp, lasth, amh, amp, axh, axp,
                                            w_full, w_att, w_maxatt, out);
}

// Round 2
// 289.891 us; speedup vs baseline: 2.3339x; 2.3339x over previous
//
#include <hip/hip_runtime.h>

#define Bq 8
#define Sq 256
#define Hq 100
#define Pq 20
#define PPq 21
#define Fq 105
#define EPSq 1e-8f
#define NEGB -1e30f

__device__ __forceinline__ unsigned fkey(float f) {
    unsigned b = __float_as_uint(f);
    return (b & 0x80000000u) ? ~b : (b | 0x80000000u);
}
__device__ __forceinline__ float funkey(unsigned k) {
    return __uint_as_float((k & 0x80000000u) ? (k ^ 0x80000000u) : ~k);
}

// ---------------- k_len: per-batch mask sums + last valid index ----------------
__global__ __launch_bounds__(256) void k_len(const int* __restrict__ mp, const int* __restrict__ mh,
                                             float* lens, int* lasts) {
    __shared__ int sp[256], sh[256];
    int b = blockIdx.x, t = threadIdx.x;
    sp[t] = mp[b * Sq + t];
    sh[t] = mh[b * Sq + t];
    __syncthreads();
    for (int o = 128; o > 0; o >>= 1) {
        if (t < o) { sp[t] += sp[t + o]; sh[t] += sh[t + o]; }
        __syncthreads();
    }
    if (t == 0) {
        int lp = sp[0], lh2 = sh[0];
        lens[b] = (float)lp;
        lens[Bq + b] = (float)lh2;
        lasts[b] = lp > 0 ? lp - 1 : 0;        // last valid premise idx
        lasts[Bq + b] = lh2 > 0 ? lh2 - 1 : 0; // last valid hyp idx
    }
}

// ---------------- k_prep: masked vectors (row+transposed), float masks, recip norms -------
// grid = 2*B*S waves of 64; side 0 = premise, 1 = hypothesis
__global__ __launch_bounds__(64) void k_prep(
    const float* __restrict__ ctx_p, const int* __restrict__ mask_p,
    const float* __restrict__ ctx_h, const int* __restrict__ mask_h,
    const float* __restrict__ w_mp,
    float* __restrict__ vm,   // [2][B][S][H]
    float* __restrict__ vmT,  // [2][B][H][S]
    float* __restrict__ mf,   // [2][B][S]
    float* __restrict__ wn) { // [2][B][PP][S] reciprocal norms (p=20 -> plain)
    int blk = blockIdx.x;
    int side = blk / (Bq * Sq);
    int rem = blk - side * (Bq * Sq);
    int b = rem / Sq, s = rem - b * Sq;
    int lane = threadIdx.x;
    const float* ctx = side ? ctx_h : ctx_p;
    const int* mask = side ? mask_h : mask_p;
    float m = (float)mask[b * Sq + s];
    const float* v = ctx + ((size_t)b * Sq + s) * Hq;
    float v1 = v[lane] * m;
    float v2 = (lane + 64 < Hq) ? v[lane + 64] * m : 0.f;
    float* vo = vm + ((size_t)side * Bq * Sq + (size_t)b * Sq + s) * Hq;
    vo[lane] = v1;
    if (lane + 64 < Hq) vo[lane + 64] = v2;
    float* vT = vmT + (size_t)(side * Bq + b) * Hq * Sq;
    vT[lane * Sq + s] = v1;
    if (lane + 64 < Hq) vT[(lane + 64) * Sq + s] = v2;
    if (lane == 0) mf[(size_t)side * Bq * Sq + b * Sq + s] = m;

    float ss = v1 * v1 + v2 * v2;
    for (int o = 32; o; o >>= 1) ss += __shfl_xor(ss, o, 64);
    float* wrow = wn + (size_t)(side * Bq + b) * PPq * Sq;
    if (lane == 0) wrow[Pq * Sq + s] = 1.f / fmaxf(sqrtf(ss), EPSq);
    for (int p = 0; p < Pq; p++) {
        float wa = w_mp[p * Hq + lane];
        float wb = (lane + 64 < Hq) ? w_mp[p * Hq + lane + 64] : 0.f;
        float t1 = wa * v1, t2 = wb * v2;
        float s2 = t1 * t1 + t2 * t2;
        for (int o = 32; o; o >>= 1) s2 += __shfl_xor(s2, o, 64);
        if (lane == 0) wrow[p * Sq + s] = 1.f / fmaxf(sqrtf(s2), EPSq);
    }
}

// ---------------- k_pw: num[p,i,j] once; row stats direct, col stats via atomics -----------
// grid = B*PP*8 blocks of 256. p==20 is the plain cos perspective (also materializes cos/cosT).
// wave w handles i = it*32 + w*8 .. +7 (A-side wave-uniform scalar ops);
// lane L handles j = 4L..4L+3 (B-side float4).
__global__ __launch_bounds__(256) void k_pw(
    const float* __restrict__ vmT, const float* __restrict__ wn,
    const float* __restrict__ mf, const float* __restrict__ w_mp,
    const float* __restrict__ lens,
    float* __restrict__ out, float* __restrict__ cosm, float* __restrict__ cosT,
    float* __restrict__ rowsum0,
    unsigned* __restrict__ colmax, float* __restrict__ colsum) {
    __shared__ float cbmax[4][Sq];
    __shared__ float cbsum[4][Sq];
    int blk = blockIdx.x;
    int b = blk / (PPq * 8);
    int rem = blk - b * (PPq * 8);
    int p = rem >> 3, it = rem & 7;
    int t = threadIdx.x;
    int lane = t & 63;
    int wid = __builtin_amdgcn_readfirstlane(t >> 6);
    int i0 = it * 32 + wid * 8;

    const float* abase = vmT + (size_t)b * Hq * Sq;          // premise [h][i]
    const float* bbase = vmT + (size_t)(Bq + b) * Hq * Sq;   // hyp     [h][j]
    const float* wp = w_mp + (p < Pq ? p : 0) * Hq;

    float4 acc[8];
#pragma unroll
    for (int k = 0; k < 8; k++) acc[k] = make_float4(0.f, 0.f, 0.f, 0.f);

#pragma unroll 2
    for (int h = 0; h < Hq; h++) {
        float4 bq = ((const float4*)(bbase + h * Sq))[lane];
        float wl = wp[h];
        float wsc = (p < Pq) ? wl * wl : 1.0f;
        bq.x *= wsc; bq.y *= wsc; bq.z *= wsc; bq.w *= wsc;
        const float4* ap = (const float4*)(abase + h * Sq + i0);
        float4 a0 = ap[0], a1 = ap[1];
        float av[8] = {a0.x, a0.y, a0.z, a0.w, a1.x, a1.y, a1.z, a1.w};
#pragma unroll
        for (int k = 0; k < 8; k++) {
            acc[k].x += av[k] * bq.x; acc[k].y += av[k] * bq.y;
            acc[k].z += av[k] * bq.z; acc[k].w += av[k] * bq.w;
        }
    }

    const float* wn0 = wn + ((size_t)b * PPq + p) * Sq;              // premise recip norms
    const float* wn1 = wn + ((size_t)(Bq + b) * PPq + p) * Sq;       // hyp recip norms
    float4 rn2 = ((const float4*)wn1)[lane];
    float4 mh4 = ((const float4*)(mf + (size_t)Bq * Sq + b * Sq))[lane];
    float invLh = 1.f / fmaxf(lens[Bq + b], EPSq);

    float cmax[4] = {NEGB, NEGB, NEGB, NEGB};
    float csum[4] = {0.f, 0.f, 0.f, 0.f};
#pragma unroll
    for (int k = 0; k < 8; k++) {
        float r1 = wn0[i0 + k];
        float4 v;
        v.x = acc[k].x * r1 * rn2.x;
        v.y = acc[k].y * r1 * rn2.y;
        v.z = acc[k].z * r1 * rn2.z;
        v.w = acc[k].w * r1 * rn2.w;
        // row stats over j (complete within wave)
        float m0 = mh4.x > 0.5f ? v.x : NEGB;
        float m1 = mh4.y > 0.5f ? v.y : NEGB;
        float m2 = mh4.z > 0.5f ? v.z : NEGB;
        float m3 = mh4.w > 0.5f ? v.w : NEGB;
        float rmax = fmaxf(fmaxf(m0, m1), fmaxf(m2, m3));
        float rs = v.x + v.y + v.z + v.w;
        for (int o = 32; o; o >>= 1) {
            rmax = fmaxf(rmax, __shfl_xor(rmax, o, 64));
            rs += __shfl_xor(rs, o, 64);
        }
        if (lane == 0) {
            float* orow = out + ((size_t)(b * Sq + i0 + k)) * Fq;
            if (p < Pq) { orow[23 + p] = rmax; orow[43 + p] = rs * invLh; }
            else { orow[0] = rmax; orow[1] = rs * invLh; rowsum0[b * Sq + i0 + k] = rs; }
        }
        // col partials (mask invalid i for max; invalid-i values are exactly 0 for sum)
        float mi = mf[b * Sq + i0 + k];
        if (mi > 0.5f) {
            cmax[0] = fmaxf(cmax[0], v.x); cmax[1] = fmaxf(cmax[1], v.y);
            cmax[2] = fmaxf(cmax[2], v.z); cmax[3] = fmaxf(cmax[3], v.w);
        }
        csum[0] += v.x; csum[1] += v.y; csum[2] += v.z; csum[3] += v.w;
        if (p == Pq) {
            ((float4*)(cosm + (size_t)(b * Sq + i0 + k) * Sq))[lane] = v;
            int jb = 4 * lane;
            cosT[((size_t)b * Sq + jb + 0) * Sq + i0 + k] = v.x;
            cosT[((size_t)b * Sq + jb + 1) * Sq + i0 + k] = v.y;
            cosT[((size_t)b * Sq + jb + 2) * Sq + i0 + k] = v.z;
            cosT[((size_t)b * Sq + jb + 3) * Sq + i0 + k] = v.w;
        }
    }
    ((float4*)&cbmax[wid][0])[lane] = make_float4(cmax[0], cmax[1], cmax[2], cmax[3]);
    ((float4*)&cbsum[wid][0])[lane] = make_float4(csum[0], csum[1], csum[2], csum[3]);
    __syncthreads();
    {
        int j = t;
        float mx = fmaxf(fmaxf(cbmax[0][j], cbmax[1][j]), fmaxf(cbmax[2][j], cbmax[3][j]));
        float sm = cbsum[0][j] + cbsum[1][j] + cbsum[2][j] + cbsum[3][j];
        size_t cidx = ((size_t)b * PPq + p) * Sq + j;
        atomicMax(colmax + cidx, fkey(mx));
        atomicAdd(colsum + cidx, sm);
    }
}

// ---------------- k_colfin: fold column stats into direction-1 output rows ----------------
__global__ __launch_bounds__(256) void k_colfin(
    const unsigned* __restrict__ colmax, const float* __restrict__ colsum,
    const float* __restrict__ lens, float* __restrict__ out, float* __restrict__ rowsum1) {
    int blk = blockIdx.x;             // b*PPq + p
    int b = blk / PPq, p = blk - b * PPq;
    int j = threadIdx.x;
    float mx = funkey(colmax[(size_t)blk * Sq + j]);
    float sm = colsum[(size_t)blk * Sq + j];
    float invLp = 1.f / fmaxf(lens[b], EPSq);
    float* orow = out + (size_t)Bq * Sq * Fq + (size_t)(b * Sq + j) * Fq;
    if (p < Pq) { orow[23 + p] = mx; orow[43 + p] = sm * invLp; }
    else { orow[0] = mx; orow[1] = sm * invLp; rowsum1[b * Sq + j] = sm; }
}

// ---------------- k_att: attention mean & masked-max vectors, both directions -------------
// grid = 2*B*(S/4) blocks of 128 (t<100 active, h=t). Block handles 4 output rows.
__global__ __launch_bounds__(128) void k_att(
    const float* __restrict__ vm, const float* __restrict__ mf,
    const float* __restrict__ cosm, const float* __restrict__ cosT,
    const float* __restrict__ rowsum0, const float* __restrict__ rowsum1,
    float* __restrict__ attv) {     // [2 dir][2 mean/max][B][S][H]
    int blk = blockIdx.x;
    int d = blk / (Bq * (Sq / 4));
    int rem = blk - d * (Bq * (Sq / 4));
    int b = rem / (Sq / 4), rt = rem - b * (Sq / 4);
    int r0 = rt * 4;
    int t = threadIdx.x;
    const float* cosR = d ? cosm : cosT;   // [b][k][r]
    const float* vB = vm + (size_t)(1 - d) * Bq * Sq * Hq + (size_t)b * Sq * Hq;
    const float* mK = mf + (size_t)(1 - d) * Bq * Sq + b * Sq;
    const float* rsW = d ? rowsum1 : rowsum0;
    float am[4] = {0.f, 0.f, 0.f, 0.f};
    float ax[4] = {NEGB, NEGB, NEGB, NEGB};
#pragma unroll 2
    for (int k = 0; k < Sq; k++) {
        float v = (t < Hq) ? vB[(size_t)k * Hq + t] : 0.f;
        const float* wrow = cosR + ((size_t)b * Sq + k) * Sq + r0;
        float w0 = wrow[0], w1 = wrow[1], w2 = wrow[2], w3 = wrow[3];
        bool mk = mK[k] > 0.5f;
        float p0 = w0 * v, p1 = w1 * v, p2 = w2 * v, p3 = w3 * v;
        am[0] += p0; am[1] += p1; am[2] += p2; am[3] += p3;
        if (mk) {
            ax[0] = fmaxf(ax[0], p0); ax[1] = fmaxf(ax[1], p1);
            ax[2] = fmaxf(ax[2], p2); ax[3] = fmaxf(ax[3], p3);
        }
    }
    if (t < Hq) {
#pragma unroll
        for (int r = 0; r < 4; r++) {
            float den = fmaxf(rsW[b * Sq + r0 + r], EPSq);
            attv[((size_t)(d * 2 + 0) * Bq * Sq + (size_t)b * Sq + r0 + r) * Hq + t] = am[r] / den;
            attv[((size_t)(d * 2 + 1) * Bq * Sq + (size_t)b * Sq + r0 + r) * Hq + t] = ax[r];
        }
    }
}

// ---------------- k_final: the three _mpm blocks (full / attentive / max-attentive) -----------
__device__ __forceinline__ void mpm_pair(float v1a, float v1b, const float* __restrict__ v2,
                                         const float* __restrict__ W, int lane,
                                         float* __restrict__ orow, int fbase) {
    float v2a = v2[lane];
    float v2b = (lane + 64 < Hq) ? v2[lane + 64] : 0.f;
    float d = v1a * v2a + v1b * v2b;
    float n1 = v1a * v1a + v1b * v1b;
    float n2 = v2a * v2a + v2b * v2b;
    for (int o = 32; o; o >>= 1) {
        d += __shfl_xor(d, o, 64);
        n1 += __shfl_xor(n1, o, 64);
        n2 += __shfl_xor(n2, o, 64);
    }
    if (lane == 0) orow[fbase] = d / (fmaxf(sqrtf(n1), EPSq) * fmaxf(sqrtf(n2), EPSq));
    for (int p = 0; p < Pq; p++) {
        float wa = W[p * Hq + lane];
        float wb = (lane + 64 < Hq) ? W[p * Hq + lane + 64] : 0.f;
        float x1 = wa * v1a, y1 = wb * v1b, x2 = wa * v2a, y2 = wb * v2b;
        float dd = x1 * x2 + y1 * y2;
        float m1 = x1 * x1 + y1 * y1;
        float m2 = x2 * x2 + y2 * y2;
        for (int o = 32; o; o >>= 1) {
            dd += __shfl_xor(dd, o, 64);
            m1 += __shfl_xor(m1, o, 64);
            m2 += __shfl_xor(m2, o, 64);
        }
        if (lane == 0) orow[fbase + 1 + p] = dd / (fmaxf(sqrtf(m1), EPSq) * fmaxf(sqrtf(m2), EPSq));
    }
}

__global__ __launch_bounds__(64) void k_final(
    const float* __restrict__ vm, const int* __restrict__ lasts,
    const float* __restrict__ attv,
    const float* __restrict__ w_full, const float* __restrict__ w_att,
    const float* __restrict__ w_maxatt,
    float* __restrict__ out) {
    int blk = blockIdx.x;
    int dir = blk / (Bq * Sq);
    int rem = blk - dir * (Bq * Sq);
    int b = rem / Sq, s = rem - b * Sq;
    int lane = threadIdx.x;
    const float* A = vm + (size_t)dir * Bq * Sq * Hq;
    const float* Ov = vm + (size_t)(1 - dir) * Bq * Sq * Hq;
    int lastO = dir ? lasts[b] : lasts[Bq + b];
    const float* v1 = A + ((size_t)b * Sq + s) * Hq;
    const float* v2full = Ov + ((size_t)b * Sq + lastO) * Hq;
    const float* v2att = attv + ((size_t)(dir * 2 + 0) * Bq * Sq + (size_t)b * Sq + s) * Hq;
    const float* v2max = attv + ((size_t)(dir * 2 + 1) * Bq * Sq + (size_t)b * Sq + s) * Hq;
    float v1a = v1[lane];
    float v1b = (lane + 64 < Hq) ? v1[lane + 64] : 0.f;
    float* orow = out + (size_t)dir * Bq * Sq * Fq + ((size_t)b * Sq + s) * Fq;
    mpm_pair(v1a, v1b, v2full, w_full, lane, orow, 2);
    mpm_pair(v1a, v1b, v2att, w_att, lane, orow, 63);
    mpm_pair(v1a, v1b, v2max, w_maxatt, lane, orow, 84);
}

extern "C" void kernel_launch(void* const* d_in, const int* in_sizes, int n_in,
                              void* d_out, int out_size, void* d_ws, size_t ws_size,
                              hipStream_t stream) {
    (void)in_sizes; (void)n_in; (void)out_size; (void)ws_size;
    const float* ctx_p    = (const float*)d_in[0];
    const int*   mask_p   = (const int*)d_in[1];
    const float* ctx_h    = (const float*)d_in[2];
    const int*   mask_h   = (const int*)d_in[3];
    const float* w_full   = (const float*)d_in[4];
    const float* w_maxpool= (const float*)d_in[5];
    const float* w_att    = (const float*)d_in[6];
    const float* w_maxatt = (const float*)d_in[7];
    float* out = (float*)d_out;
    float* ws = (float*)d_ws;

    const size_t BSH = (size_t)Bq * Sq * Hq;   // 204800
    const size_t BS  = (size_t)Bq * Sq;        // 2048
    const size_t BSS = (size_t)Bq * Sq * Sq;   // 524288
    const size_t BPS = (size_t)Bq * PPq * Sq;  // 43008

    float* vm     = ws;               ws += 2 * BSH;
    float* vmT    = ws;               ws += 2 * BSH;
    float* mf     = ws;               ws += 2 * BS;
    float* wn     = ws;               ws += 2 * BPS;
    float* cosm   = ws;               ws += BSS;
    float* cosT   = ws;               ws += BSS;
    float* rowsum0= ws;               ws += BS;
    float* rowsum1= ws;               ws += BS;
    unsigned* colmax = (unsigned*)ws; ws += BPS;
    float* colsum = ws;               ws += BPS;   // contiguous after colmax (one memset)
    float* attv   = ws;               ws += 4 * BSH;
    float* lens   = ws;               ws += 16;
    int*   lasts  = (int*)ws;         ws += 16;

    hipMemsetAsync(colmax, 0, 2 * BPS * sizeof(float), stream);  // colmax key(−max) = 0; colsum = 0
    k_len<<<Bq, 256, 0, stream>>>(mask_p, mask_h, lens, lasts);
    k_prep<<<2 * Bq * Sq, 64, 0, stream>>>(ctx_p, mask_p, ctx_h, mask_h, w_maxpool,
                                           vm, vmT, mf, wn);
    k_pw<<<Bq * PPq * 8, 256, 0, stream>>>(vmT, wn, mf, w_maxpool, lens,
                                           out, cosm, cosT, rowsum0, colmax, colsum);
    k_colfin<<<Bq * PPq, 256, 0, stream>>>(colmax, colsum, lens, out, rowsum1);
    k_att<<<2 * Bq * (Sq / 4), 128, 0, stream>>>(vm, mf, cosm, cosT, rowsum0, rowsum1, attv);
    k_final<<<2 * Bq * Sq, 64, 0, stream>>>(vm, lasts, attv, w_full, w_att, w_maxatt, out);
}

// Round 3
// 236.411 us; speedup vs baseline: 2.8618x; 1.2262x over previous
//
#include <hip/hip_runtime.h>

#define Bq 8
#define Sq 256
#define Hq 100
#define Pq 20
#define PPq 21
#define Fq 105
#define EPSq 1e-8f
#define NEGB -1e30f

__device__ __forceinline__ unsigned fkey(float f) {
    unsigned b = __float_as_uint(f);
    return (b & 0x80000000u) ? ~b : (b | 0x80000000u);
}
__device__ __forceinline__ float funkey(unsigned k) {
    return __uint_as_float((k & 0x80000000u) ? (k ^ 0x80000000u) : ~k);
}

// ---------------- k_len: per-batch mask sums + last valid index ----------------
__global__ __launch_bounds__(256) void k_len(const int* __restrict__ mp, const int* __restrict__ mh,
                                             float* lens, int* lasts) {
    __shared__ int sp[256], sh[256];
    int b = blockIdx.x, t = threadIdx.x;
    sp[t] = mp[b * Sq + t];
    sh[t] = mh[b * Sq + t];
    __syncthreads();
    for (int o = 128; o > 0; o >>= 1) {
        if (t < o) { sp[t] += sp[t + o]; sh[t] += sh[t + o]; }
        __syncthreads();
    }
    if (t == 0) {
        int lp = sp[0], lh2 = sh[0];
        lens[b] = (float)lp;
        lens[Bq + b] = (float)lh2;
        lasts[b] = lp > 0 ? lp - 1 : 0;
        lasts[Bq + b] = lh2 > 0 ? lh2 - 1 : 0;
    }
}

// ---------------- k_prep: masked vm/vmT, float mask, 21 recip norms — no shuffles ---------
// grid = 16 blocks (side*8 + b), 256 threads (thread = token s)
__global__ __launch_bounds__(256) void k_prep(
    const float* __restrict__ ctx_p, const int* __restrict__ mask_p,
    const float* __restrict__ ctx_h, const int* __restrict__ mask_h,
    const float* __restrict__ w_mp,
    float* __restrict__ vm,   // [2][B][S][H]
    float* __restrict__ vmT,  // [2][B][H][S]
    float* __restrict__ mf,   // [2][B][S]
    float* __restrict__ wn) { // [2][B][PP][S] reciprocal norms (p=20 -> plain)
    __shared__ float tileT[Hq * 257];   // [h][s], pad stride 257
    __shared__ float w2T[Hq * 20];      // [h][p] = w^2
    __shared__ float smf[256];
    int side = blockIdx.x >> 3;
    int b = blockIdx.x & 7;
    int t = threadIdx.x;
    const float* ctx = side ? ctx_h : ctx_p;
    const int* mask = side ? mask_h : mask_p;
    smf[t] = (float)mask[b * Sq + t];
    for (int idx = t; idx < Pq * Hq; idx += 256) {
        int p = idx / Hq, h = idx - p * Hq;
        float w = w_mp[idx];
        w2T[h * 20 + p] = w * w;
    }
    __syncthreads();

    const float4* src = (const float4*)(ctx + (size_t)b * Sq * Hq);
    float4* vmo = (float4*)(vm + ((size_t)side * Bq + b) * Sq * Hq);
#pragma unroll
    for (int q = 0; q < 25; q++) {
        int F = t + 256 * q;
        int s = F / 25;
        int c = F - s * 25;
        float m = smf[s];
        float4 v4 = src[F];
        v4.x *= m; v4.y *= m; v4.z *= m; v4.w *= m;
        vmo[F] = v4;
        int h0 = c * 4;
        tileT[(h0 + 0) * 257 + s] = v4.x;
        tileT[(h0 + 1) * 257 + s] = v4.y;
        tileT[(h0 + 2) * 257 + s] = v4.z;
        tileT[(h0 + 3) * 257 + s] = v4.w;
    }
    __syncthreads();

    int s = t;
    float acc[PPq];
#pragma unroll
    for (int p = 0; p < PPq; p++) acc[p] = 0.f;
    float* vmTo = vmT + ((size_t)side * Bq + b) * Hq * Sq;
    for (int h = 0; h < Hq; h++) {
        float v = tileT[h * 257 + s];
        vmTo[h * Sq + s] = v;
        float e = v * v;
        acc[Pq] += e;
        const float4* wrow = (const float4*)(w2T + h * 20);
#pragma unroll
        for (int pq = 0; pq < 5; pq++) {
            float4 w4 = wrow[pq];
            acc[pq * 4 + 0] += w4.x * e;
            acc[pq * 4 + 1] += w4.y * e;
            acc[pq * 4 + 2] += w4.z * e;
            acc[pq * 4 + 3] += w4.w * e;
        }
    }
    float* wout = wn + ((size_t)side * Bq + b) * PPq * Sq;
#pragma unroll
    for (int p = 0; p < PPq; p++)
        wout[p * Sq + s] = 1.f / fmaxf(sqrtf(acc[p]), EPSq);
    mf[(size_t)side * Bq * Sq + b * Sq + s] = smf[s];
}

// ---------------- k_pw: num[p,i,j] once; row stats direct, col stats via atomics -----------
__global__ __launch_bounds__(256) void k_pw(
    const float* __restrict__ vmT, const float* __restrict__ wn,
    const float* __restrict__ mf, const float* __restrict__ w_mp,
    const float* __restrict__ lens,
    float* __restrict__ out, float* __restrict__ cosm, float* __restrict__ cosT,
    float* __restrict__ rowsum0,
    unsigned* __restrict__ colmax, float* __restrict__ colsum) {
    __shared__ float cbmax[4][Sq];
    __shared__ float cbsum[4][Sq];
    int blk = blockIdx.x;
    int b = blk / (PPq * 8);
    int rem = blk - b * (PPq * 8);
    int p = rem >> 3, it = rem & 7;
    int t = threadIdx.x;
    int lane = t & 63;
    int wid = __builtin_amdgcn_readfirstlane(t >> 6);
    int i0 = it * 32 + wid * 8;

    const float* abase = vmT + (size_t)b * Hq * Sq;
    const float* bbase = vmT + (size_t)(Bq + b) * Hq * Sq;
    const float* wp = w_mp + (p < Pq ? p : 0) * Hq;

    float4 acc[8];
#pragma unroll
    for (int k = 0; k < 8; k++) acc[k] = make_float4(0.f, 0.f, 0.f, 0.f);

#pragma unroll 4
    for (int h = 0; h < Hq; h++) {
        float4 bq = ((const float4*)(bbase + h * Sq))[lane];
        float wl = wp[h];
        float wsc = (p < Pq) ? wl * wl : 1.0f;
        bq.x *= wsc; bq.y *= wsc; bq.z *= wsc; bq.w *= wsc;
        const float4* ap = (const float4*)(abase + h * Sq + i0);
        float4 a0 = ap[0], a1 = ap[1];
        float av[8] = {a0.x, a0.y, a0.z, a0.w, a1.x, a1.y, a1.z, a1.w};
#pragma unroll
        for (int k = 0; k < 8; k++) {
            acc[k].x += av[k] * bq.x; acc[k].y += av[k] * bq.y;
            acc[k].z += av[k] * bq.z; acc[k].w += av[k] * bq.w;
        }
    }

    const float* wn0 = wn + ((size_t)b * PPq + p) * Sq;
    const float* wn1 = wn + ((size_t)(Bq + b) * PPq + p) * Sq;
    float4 rn2 = ((const float4*)wn1)[lane];
    float4 mh4 = ((const float4*)(mf + (size_t)Bq * Sq + b * Sq))[lane];
    float invLh = 1.f / fmaxf(lens[Bq + b], EPSq);

    float cmax[4] = {NEGB, NEGB, NEGB, NEGB};
    float csum[4] = {0.f, 0.f, 0.f, 0.f};
#pragma unroll
    for (int k = 0; k < 8; k++) {
        float r1 = wn0[i0 + k];
        float4 v;
        v.x = acc[k].x * r1 * rn2.x;
        v.y = acc[k].y * r1 * rn2.y;
        v.z = acc[k].z * r1 * rn2.z;
        v.w = acc[k].w * r1 * rn2.w;
        float m0 = mh4.x > 0.5f ? v.x : NEGB;
        float m1 = mh4.y > 0.5f ? v.y : NEGB;
        float m2 = mh4.z > 0.5f ? v.z : NEGB;
        float m3 = mh4.w > 0.5f ? v.w : NEGB;
        float rmax = fmaxf(fmaxf(m0, m1), fmaxf(m2, m3));
        float rs = v.x + v.y + v.z + v.w;
        for (int o = 32; o; o >>= 1) {
            rmax = fmaxf(rmax, __shfl_xor(rmax, o, 64));
            rs += __shfl_xor(rs, o, 64);
        }
        if (lane == 0) {
            float* orow = out + ((size_t)(b * Sq + i0 + k)) * Fq;
            if (p < Pq) { orow[23 + p] = rmax; orow[43 + p] = rs * invLh; }
            else { orow[0] = rmax; orow[1] = rs * invLh; rowsum0[b * Sq + i0 + k] = rs; }
        }
        float mi = mf[b * Sq + i0 + k];
        if (mi > 0.5f) {
            cmax[0] = fmaxf(cmax[0], v.x); cmax[1] = fmaxf(cmax[1], v.y);
            cmax[2] = fmaxf(cmax[2], v.z); cmax[3] = fmaxf(cmax[3], v.w);
        }
        csum[0] += v.x; csum[1] += v.y; csum[2] += v.z; csum[3] += v.w;
        if (p == Pq) {
            ((float4*)(cosm + (size_t)(b * Sq + i0 + k) * Sq))[lane] = v;
            int jb = 4 * lane;
            cosT[((size_t)b * Sq + jb + 0) * Sq + i0 + k] = v.x;
            cosT[((size_t)b * Sq + jb + 1) * Sq + i0 + k] = v.y;
            cosT[((size_t)b * Sq + jb + 2) * Sq + i0 + k] = v.z;
            cosT[((size_t)b * Sq + jb + 3) * Sq + i0 + k] = v.w;
        }
    }
    ((float4*)&cbmax[wid][0])[lane] = make_float4(cmax[0], cmax[1], cmax[2], cmax[3]);
    ((float4*)&cbsum[wid][0])[lane] = make_float4(csum[0], csum[1], csum[2], csum[3]);
    __syncthreads();
    {
        int j = t;
        float mx = fmaxf(fmaxf(cbmax[0][j], cbmax[1][j]), fmaxf(cbmax[2][j], cbmax[3][j]));
        float sm = cbsum[0][j] + cbsum[1][j] + cbsum[2][j] + cbsum[3][j];
        size_t cidx = ((size_t)b * PPq + p) * Sq + j;
        atomicMax(colmax + cidx, fkey(mx));
        atomicAdd(colsum + cidx, sm);
    }
}

// ---------------- k_colfin: fold column stats into direction-1 output rows ----------------
__global__ __launch_bounds__(256) void k_colfin(
    const unsigned* __restrict__ colmax, const float* __restrict__ colsum,
    const float* __restrict__ lens, float* __restrict__ out, float* __restrict__ rowsum1) {
    int blk = blockIdx.x;
    int b = blk / PPq, p = blk - b * PPq;
    int j = threadIdx.x;
    float mx = funkey(colmax[(size_t)blk * Sq + j]);
    float sm = colsum[(size_t)blk * Sq + j];
    float invLp = 1.f / fmaxf(lens[b], EPSq);
    float* orow = out + (size_t)Bq * Sq * Fq + (size_t)(b * Sq + j) * Fq;
    if (p < Pq) { orow[23 + p] = mx; orow[43 + p] = sm * invLp; }
    else { orow[0] = mx; orow[1] = sm * invLp; rowsum1[b * Sq + j] = sm; }
}

// ---------------- k_att: attention mean & masked-max, tiled, writes TRANSPOSED ------------
// grid = 2*Bq*16 (d, b, 16-r tile), 256 threads: h = t&127, rh = t>>7 (8 r's each)
__global__ __launch_bounds__(256) void k_att(
    const float* __restrict__ vm, const float* __restrict__ mf,
    const float* __restrict__ cosm, const float* __restrict__ cosT,
    const float* __restrict__ rowsum0, const float* __restrict__ rowsum1,
    float* __restrict__ attvT) {    // [2d*2j][B][H][S]
    __shared__ float L[Sq * 20];    // [k][16 r + pad]
    __shared__ float smk[256];
    int blk = blockIdx.x;
    int d = blk >> 7;               // / (Bq*16)
    int rem = blk & 127;
    int b = rem >> 4, rt = rem & 15;
    int r0 = rt * 16;
    int t = threadIdx.x;
    int h = t & 127, rh = t >> 7;

    const float* src = (d ? cosm : cosT) + (size_t)b * Sq * Sq;   // [k][r-cols]
#pragma unroll
    for (int q = 0; q < 4; q++) {
        int F = t + 256 * q;
        int k = F >> 2, c = F & 3;
        float4 v4 = ((const float4*)(src + (size_t)k * Sq + r0))[c];
        ((float4*)(L + k * 20 + c * 4))[0] = v4;
    }
    smk[t] = mf[(size_t)(1 - d) * Bq * Sq + b * Sq + t];
    __syncthreads();

    const float* vB = vm + (size_t)(1 - d) * Bq * Sq * Hq + (size_t)b * Sq * Hq;
    float am[8], ax[8];
#pragma unroll
    for (int r = 0; r < 8; r++) { am[r] = 0.f; ax[r] = NEGB; }
#pragma unroll 2
    for (int k = 0; k < Sq; k++) {
        float v = (h < Hq) ? vB[(size_t)k * Hq + h] : 0.f;
        float4 w0 = ((const float4*)(L + k * 20 + rh * 8))[0];
        float4 w1 = ((const float4*)(L + k * 20 + rh * 8))[1];
        float wv[8] = {w0.x, w0.y, w0.z, w0.w, w1.x, w1.y, w1.z, w1.w};
        bool mk = smk[k] > 0.5f;
#pragma unroll
        for (int r = 0; r < 8; r++) {
            float pr = wv[r] * v;
            am[r] += pr;
            if (mk) ax[r] = fmaxf(ax[r], pr);
        }
    }
    if (h < Hq) {
        const float* rsW = d ? rowsum1 : rowsum0;
        int rb = r0 + rh * 8;
        float* om = attvT + (((size_t)(d * 2 + 0) * Bq + b) * Hq + h) * Sq + rb;
        float* ox = attvT + (((size_t)(d * 2 + 1) * Bq + b) * Hq + h) * Sq + rb;
#pragma unroll
        for (int r = 0; r < 8; r++) {
            float den = fmaxf(rsW[b * Sq + rb + r], EPSq);
            om[r] = am[r] / den;
            ox[r] = ax[r];
        }
    }
}

// ---------------- k_final: full/att/maxatt _mpm — register accumulators, no shuffles ------
// grid = 3m * 2dir * Bq = 48 blocks, 256 threads (thread = token s)
__global__ __launch_bounds__(256) void k_final(
    const float* __restrict__ vm, const float* __restrict__ vmT,
    const int* __restrict__ lasts, const float* __restrict__ attvT,
    const float* __restrict__ w_full, const float* __restrict__ w_att,
    const float* __restrict__ w_maxatt,
    float* __restrict__ out) {
    __shared__ float w2T[Hq * 20];   // [h][p]
    __shared__ float v2u[Hq];
    int blk = blockIdx.x;
    int m = blk / 16;
    int rem = blk & 15;
    int dir = rem >> 3, b = rem & 7;
    int t = threadIdx.x;
    const float* W = (m == 0) ? w_full : (m == 1) ? w_att : w_maxatt;
    for (int idx = t; idx < Pq * Hq; idx += 256) {
        int p = idx / Hq, h = idx - p * Hq;
        float w = W[idx];
        w2T[h * 20 + p] = w * w;
    }
    if (m == 0 && t < Hq) {
        int lastO = dir ? lasts[b] : lasts[Bq + b];
        v2u[t] = vm[(size_t)(1 - dir) * Bq * Sq * Hq + ((size_t)b * Sq + lastO) * Hq + t];
    }
    __syncthreads();

    int s = t;
    const float* v1T = vmT + (size_t)(dir * Bq + b) * Hq * Sq;
    const float* v2T = attvT + ((size_t)(dir * 2 + (m == 2 ? 1 : 0)) * Bq + b) * Hq * Sq;

    float dotp[Pq], n1p[Pq], n2p[Pq];
#pragma unroll
    for (int p = 0; p < Pq; p++) { dotp[p] = 0.f; n1p[p] = 0.f; n2p[p] = 0.f; }
    float pd = 0.f, p1 = 0.f, p2 = 0.f;
    for (int h = 0; h < Hq; h++) {
        float v1 = v1T[h * Sq + s];
        float v2 = (m == 0) ? v2u[h] : v2T[h * Sq + s];
        float e1 = v1 * v2, e2 = v1 * v1, e3 = v2 * v2;
        pd += e1; p1 += e2; p2 += e3;
        const float4* wrow = (const float4*)(w2T + h * 20);
#pragma unroll
        for (int pq = 0; pq < 5; pq++) {
            float4 w4 = wrow[pq];
            dotp[pq * 4 + 0] += w4.x * e1; n1p[pq * 4 + 0] += w4.x * e2; n2p[pq * 4 + 0] += w4.x * e3;
            dotp[pq * 4 + 1] += w4.y * e1; n1p[pq * 4 + 1] += w4.y * e2; n2p[pq * 4 + 1] += w4.y * e3;
            dotp[pq * 4 + 2] += w4.z * e1; n1p[pq * 4 + 2] += w4.z * e2; n2p[pq * 4 + 2] += w4.z * e3;
            dotp[pq * 4 + 3] += w4.w * e1; n1p[pq * 4 + 3] += w4.w * e2; n2p[pq * 4 + 3] += w4.w * e3;
        }
    }
    int fbase = (m == 0) ? 2 : (m == 1) ? 63 : 84;
    float* orow = out + (size_t)dir * Bq * Sq * Fq + ((size_t)b * Sq + s) * Fq;
    orow[fbase] = pd / (fmaxf(sqrtf(p1), EPSq) * fmaxf(sqrtf(p2), EPSq));
#pragma unroll
    for (int p = 0; p < Pq; p++)
        orow[fbase + 1 + p] = dotp[p] / (fmaxf(sqrtf(n1p[p]), EPSq) * fmaxf(sqrtf(n2p[p]), EPSq));
}

extern "C" void kernel_launch(void* const* d_in, const int* in_sizes, int n_in,
                              void* d_out, int out_size, void* d_ws, size_t ws_size,
                              hipStream_t stream) {
    (void)in_sizes; (void)n_in; (void)out_size; (void)ws_size;
    const float* ctx_p    = (const float*)d_in[0];
    const int*   mask_p   = (const int*)d_in[1];
    const float* ctx_h    = (const float*)d_in[2];
    const int*   mask_h   = (const int*)d_in[3];
    const float* w_full   = (const float*)d_in[4];
    const float* w_maxpool= (const float*)d_in[5];
    const float* w_att    = (const float*)d_in[6];
    const float* w_maxatt = (const float*)d_in[7];
    float* out = (float*)d_out;
    float* ws = (float*)d_ws;

    const size_t BSH = (size_t)Bq * Sq * Hq;   // 204800
    const size_t BS  = (size_t)Bq * Sq;        // 2048
    const size_t BSS = (size_t)Bq * Sq * Sq;   // 524288
    const size_t BPS = (size_t)Bq * PPq * Sq;  // 43008

    float* vm     = ws;               ws += 2 * BSH;
    float* vmT    = ws;               ws += 2 * BSH;
    float* mf     = ws;               ws += 2 * BS;
    float* wn     = ws;               ws += 2 * BPS;
    float* cosm   = ws;               ws += BSS;
    float* cosT   = ws;               ws += BSS;
    float* rowsum0= ws;               ws += BS;
    float* rowsum1= ws;               ws += BS;
    unsigned* colmax = (unsigned*)ws; ws += BPS;
    float* colsum = ws;               ws += BPS;
    float* attvT  = ws;               ws += 4 * BSH;
    float* lens   = ws;               ws += 16;
    int*   lasts  = (int*)ws;         ws += 16;

    hipMemsetAsync(colmax, 0, 2 * BPS * sizeof(float), stream);
    k_len<<<Bq, 256, 0, stream>>>(mask_p, mask_h, lens, lasts);
    k_prep<<<16, 256, 0, stream>>>(ctx_p, mask_p, ctx_h, mask_h, w_maxpool,
                                   vm, vmT, mf, wn);
    k_pw<<<Bq * PPq * 8, 256, 0, stream>>>(vmT, wn, mf, w_maxpool, lens,
                                           out, cosm, cosT, rowsum0, colmax, colsum);
    k_colfin<<<Bq * PPq, 256, 0, stream>>>(colmax, colsum, lens, out, rowsum1);
    k_att<<<2 * Bq * 16, 256, 0, stream>>>(vm, mf, cosm, cosT, rowsum0, rowsum1, attvT);
    k_final<<<48, 256, 0, stream>>>(vm, vmT, lasts, attvT, w_full, w_att, w_maxatt, out);
}

// Round 4
// 188.744 us; speedup vs baseline: 3.5846x; 1.2526x over previous
//
#include <hip/hip_runtime.h>

#define Bq 8
#define Sq 256
#define Hq 100
#define Pq 20
#define PPq 21
#define Fq 105
#define EPSq 1e-8f
#define NEGB -1e30f

__device__ __forceinline__ unsigned fkey(float f) {
    unsigned b = __float_as_uint(f);
    return (b & 0x80000000u) ? ~b : (b | 0x80000000u);
}
__device__ __forceinline__ float funkey(unsigned k) {
    return __uint_as_float((k & 0x80000000u) ? (k ^ 0x80000000u) : ~k);
}

// ---------------- k_prep: masks+lens, masked vm/vmT, 21 recip norms, zero col bufs --------
// grid = 16 blocks (side*8 + b), 256 threads (thread = token s)
__global__ __launch_bounds__(256) void k_prep(
    const float* __restrict__ ctx_p, const int* __restrict__ mask_p,
    const float* __restrict__ ctx_h, const int* __restrict__ mask_h,
    const float* __restrict__ w_mp,
    float* __restrict__ vm,   // [2][B][S][H]
    float* __restrict__ vmT,  // [2][B][H][S]
    float* __restrict__ mf,   // [2][B][S]
    float* __restrict__ wn,   // [2][B][PP][S] reciprocal norms (p=20 -> plain)
    float* __restrict__ lens, int* __restrict__ lasts,
    unsigned* __restrict__ colinit) {   // 2*B*PP*S words to zero
    __shared__ float tileT[Hq * 257];   // [h][s], pad stride 257
    __shared__ float w2T[Hq * 20];      // [h][p] = w^2
    __shared__ float smf[256];
    __shared__ int ired[256];
    int side = blockIdx.x >> 3;
    int b = blockIdx.x & 7;
    int t = threadIdx.x;

    for (int idx = blockIdx.x * 256 + t; idx < 2 * Bq * PPq * Sq; idx += 16 * 256)
        colinit[idx] = 0u;

    const float* ctx = side ? ctx_h : ctx_p;
    const int* mask = side ? mask_h : mask_p;
    int mi = mask[b * Sq + t];
    smf[t] = (float)mi;
    ired[t] = mi;
    for (int idx = t; idx < Pq * Hq; idx += 256) {
        int p = idx / Hq, h = idx - p * Hq;
        float w = w_mp[idx];
        w2T[h * 20 + p] = w * w;
    }
    __syncthreads();
    for (int o = 128; o; o >>= 1) {
        if (t < o) ired[t] += ired[t + o];
        __syncthreads();
    }
    if (t == 0) {
        int l = ired[0];
        lens[side * Bq + b] = (float)l;
        lasts[side * Bq + b] = l > 0 ? l - 1 : 0;
    }

    const float4* src = (const float4*)(ctx + (size_t)b * Sq * Hq);
    float4* vmo = (float4*)(vm + ((size_t)side * Bq + b) * Sq * Hq);
#pragma unroll
    for (int q = 0; q < 25; q++) {
        int F = t + 256 * q;
        int s = F / 25;
        int c = F - s * 25;
        float m = smf[s];
        float4 v4 = src[F];
        v4.x *= m; v4.y *= m; v4.z *= m; v4.w *= m;
        vmo[F] = v4;
        int h0 = c * 4;
        tileT[(h0 + 0) * 257 + s] = v4.x;
        tileT[(h0 + 1) * 257 + s] = v4.y;
        tileT[(h0 + 2) * 257 + s] = v4.z;
        tileT[(h0 + 3) * 257 + s] = v4.w;
    }
    __syncthreads();

    int s = t;
    float acc[PPq];
#pragma unroll
    for (int p = 0; p < PPq; p++) acc[p] = 0.f;
    float* vmTo = vmT + ((size_t)side * Bq + b) * Hq * Sq;
    for (int h = 0; h < Hq; h++) {
        float v = tileT[h * 257 + s];
        vmTo[h * Sq + s] = v;
        float e = v * v;
        acc[Pq] += e;
        const float4* wrow = (const float4*)(w2T + h * 20);
#pragma unroll
        for (int pq = 0; pq < 5; pq++) {
            float4 w4 = wrow[pq];
            acc[pq * 4 + 0] += w4.x * e;
            acc[pq * 4 + 1] += w4.y * e;
            acc[pq * 4 + 2] += w4.z * e;
            acc[pq * 4 + 3] += w4.w * e;
        }
    }
    float* wout = wn + ((size_t)side * Bq + b) * PPq * Sq;
#pragma unroll
    for (int p = 0; p < PPq; p++)
        wout[p * Sq + s] = 1.f / fmaxf(sqrtf(acc[p]), EPSq);
    mf[(size_t)side * Bq * Sq + b * Sq + s] = smf[s];
}

// ---------------- k_pw: num[p,i,j] once; row stats direct, col stats via atomics -----------
// grid = B*PP*4 blocks of 256; wave handles 16 i's, lane handles 4 j's.
__global__ __launch_bounds__(256) void k_pw(
    const float* __restrict__ vmT, const float* __restrict__ wn,
    const float* __restrict__ mf, const float* __restrict__ w_mp,
    const float* __restrict__ lens,
    float* __restrict__ out, float* __restrict__ cosm, float* __restrict__ cosT,
    unsigned* __restrict__ colmax, float* __restrict__ colsum) {
    __shared__ float cbmax[4][Sq];
    __shared__ float cbsum[4][Sq];
    int blk = blockIdx.x;
    int b = blk / (PPq * 4);
    int rem = blk - b * (PPq * 4);
    int p = rem >> 2, it = rem & 3;
    int t = threadIdx.x;
    int lane = t & 63;
    int wid = __builtin_amdgcn_readfirstlane(t >> 6);
    int i0 = it * 64 + wid * 16;

    const float* abase = vmT + (size_t)b * Hq * Sq;
    const float* bbase = vmT + (size_t)(Bq + b) * Hq * Sq;
    const float* wp = w_mp + (p < Pq ? p : 0) * Hq;

    float4 acc[16];
#pragma unroll
    for (int k = 0; k < 16; k++) acc[k] = make_float4(0.f, 0.f, 0.f, 0.f);

#pragma unroll 2
    for (int h = 0; h < Hq; h++) {
        float4 bq = ((const float4*)(bbase + h * Sq))[lane];
        float wl = wp[h];
        float wsc = (p < Pq) ? wl * wl : 1.0f;
        bq.x *= wsc; bq.y *= wsc; bq.z *= wsc; bq.w *= wsc;
        const float4* ap = (const float4*)(abase + h * Sq + i0);
        float4 a0 = ap[0], a1 = ap[1], a2 = ap[2], a3 = ap[3];
        float av[16] = {a0.x, a0.y, a0.z, a0.w, a1.x, a1.y, a1.z, a1.w,
                        a2.x, a2.y, a2.z, a2.w, a3.x, a3.y, a3.z, a3.w};
#pragma unroll
        for (int k = 0; k < 16; k++) {
            acc[k].x += av[k] * bq.x; acc[k].y += av[k] * bq.y;
            acc[k].z += av[k] * bq.z; acc[k].w += av[k] * bq.w;
        }
    }

    const float* wn0 = wn + ((size_t)b * PPq + p) * Sq;
    const float* wn1 = wn + ((size_t)(Bq + b) * PPq + p) * Sq;
    float4 rn2 = ((const float4*)wn1)[lane];
    float4 mh4 = ((const float4*)(mf + (size_t)Bq * Sq + b * Sq))[lane];
    float invLh = 1.f / fmaxf(lens[Bq + b], EPSq);

    float cmax[4] = {NEGB, NEGB, NEGB, NEGB};
    float csum[4] = {0.f, 0.f, 0.f, 0.f};
#pragma unroll
    for (int k = 0; k < 16; k++) {
        float r1 = wn0[i0 + k];
        float4 v;
        v.x = acc[k].x * r1 * rn2.x;
        v.y = acc[k].y * r1 * rn2.y;
        v.z = acc[k].z * r1 * rn2.z;
        v.w = acc[k].w * r1 * rn2.w;
        float m0 = mh4.x > 0.5f ? v.x : NEGB;
        float m1 = mh4.y > 0.5f ? v.y : NEGB;
        float m2 = mh4.z > 0.5f ? v.z : NEGB;
        float m3 = mh4.w > 0.5f ? v.w : NEGB;
        float rmax = fmaxf(fmaxf(m0, m1), fmaxf(m2, m3));
        float rs = v.x + v.y + v.z + v.w;
        for (int o = 32; o; o >>= 1) {
            rmax = fmaxf(rmax, __shfl_xor(rmax, o, 64));
            rs += __shfl_xor(rs, o, 64);
        }
        if (lane == 0) {
            float* orow = out + ((size_t)(b * Sq + i0 + k)) * Fq;
            if (p < Pq) { orow[23 + p] = rmax; orow[43 + p] = rs * invLh; }
            else { orow[0] = rmax; orow[1] = rs * invLh; }
        }
        float mi = mf[b * Sq + i0 + k];
        if (mi > 0.5f) {
            cmax[0] = fmaxf(cmax[0], v.x); cmax[1] = fmaxf(cmax[1], v.y);
            cmax[2] = fmaxf(cmax[2], v.z); cmax[3] = fmaxf(cmax[3], v.w);
        }
        csum[0] += v.x; csum[1] += v.y; csum[2] += v.z; csum[3] += v.w;
        if (p == Pq) {
            ((float4*)(cosm + (size_t)(b * Sq + i0 + k) * Sq))[lane] = v;
            int jb = 4 * lane;
            cosT[((size_t)b * Sq + jb + 0) * Sq + i0 + k] = v.x;
            cosT[((size_t)b * Sq + jb + 1) * Sq + i0 + k] = v.y;
            cosT[((size_t)b * Sq + jb + 2) * Sq + i0 + k] = v.z;
            cosT[((size_t)b * Sq + jb + 3) * Sq + i0 + k] = v.w;
        }
    }
    ((float4*)&cbmax[wid][0])[lane] = make_float4(cmax[0], cmax[1], cmax[2], cmax[3]);
    ((float4*)&cbsum[wid][0])[lane] = make_float4(csum[0], csum[1], csum[2], csum[3]);
    __syncthreads();
    {
        int j = t;
        float mx = fmaxf(fmaxf(cbmax[0][j], cbmax[1][j]), fmaxf(cbmax[2][j], cbmax[3][j]));
        float sm = cbsum[0][j] + cbsum[1][j] + cbsum[2][j] + cbsum[3][j];
        size_t cidx = ((size_t)b * PPq + p) * Sq + j;
        atomicMax(colmax + cidx, fkey(mx));
        atomicAdd(colsum + cidx, sm);
    }
}

// ---------------- k_att: attention raw-sum & masked-max vectors (+ merged colfin) ---------
// grid = 2d*8b*32rt = 512 blocks, 256 threads: h = t&127, rh = t>>7 (4 r's each)
__global__ __launch_bounds__(256) void k_att(
    const float* __restrict__ vm, const float* __restrict__ mf,
    const float* __restrict__ cosm, const float* __restrict__ cosT,
    const unsigned* __restrict__ colmax, const float* __restrict__ colsum,
    const float* __restrict__ lens,
    float* __restrict__ out,
    float* __restrict__ attvT) {    // [2d*2j][B][H][S]
    __shared__ float L[Sq * 8];     // [k][8 r]
    __shared__ float bm[Sq];        // 0 valid / NEGB invalid
    int blk = blockIdx.x;
    int t = threadIdx.x;

    // merged column-stat fold (dir-1 rows), blocks 0..167
    if (blk < Bq * PPq) {
        int bcf = blk / PPq, pcf = blk - bcf * PPq;
        float mx = funkey(colmax[(size_t)blk * Sq + t]);
        float sm = colsum[(size_t)blk * Sq + t];
        float invLp = 1.f / fmaxf(lens[bcf], EPSq);
        float* orow = out + (size_t)Bq * Sq * Fq + (size_t)(bcf * Sq + t) * Fq;
        if (pcf < Pq) { orow[23 + pcf] = mx; orow[43 + pcf] = sm * invLp; }
        else { orow[0] = mx; orow[1] = sm * invLp; }
    }

    int d = blk >> 8;
    int rem = blk & 255;
    int b = rem >> 5, rt = rem & 31;
    int r0 = rt * 8;
    int h = t & 127, rh = t >> 7;

    const float* src = (d ? cosm : cosT) + (size_t)b * Sq * Sq;   // [k][r-cols]
#pragma unroll
    for (int q = 0; q < 2; q++) {
        int F = t + 256 * q;
        int k = F >> 1, c = F & 1;
        float4 v4 = *(const float4*)(src + (size_t)k * Sq + r0 + c * 4);
        *(float4*)(L + k * 8 + c * 4) = v4;
    }
    bm[t] = (mf[(size_t)(1 - d) * Bq * Sq + b * Sq + t] > 0.5f) ? 0.f : NEGB;
    __syncthreads();

    const float* vB = vm + (size_t)(1 - d) * Bq * Sq * Hq + (size_t)b * Sq * Hq + h;
    bool hv = (h < Hq);
    float am[4] = {0.f, 0.f, 0.f, 0.f};
    float ax[4] = {NEGB, NEGB, NEGB, NEGB};
#pragma unroll 8
    for (int k = 0; k < Sq; k++) {
        float v = hv ? vB[(size_t)k * Hq] : 0.f;
        float4 w = *(const float4*)(L + k * 8 + rh * 4);
        float bk = bm[k];
        float p0 = w.x * v, p1 = w.y * v, p2 = w.z * v, p3 = w.w * v;
        am[0] += p0; am[1] += p1; am[2] += p2; am[3] += p3;
        ax[0] = fmaxf(ax[0], p0 + bk); ax[1] = fmaxf(ax[1], p1 + bk);
        ax[2] = fmaxf(ax[2], p2 + bk); ax[3] = fmaxf(ax[3], p3 + bk);
    }
    if (hv) {
        int rb = r0 + rh * 4;
        float4 m4 = make_float4(am[0], am[1], am[2], am[3]);
        float4 x4 = make_float4(ax[0], ax[1], ax[2], ax[3]);
        *(float4*)(attvT + (((size_t)(d * 2 + 0) * Bq + b) * Hq + h) * Sq + rb) = m4;
        *(float4*)(attvT + (((size_t)(d * 2 + 1) * Bq + b) * Hq + h) * Sq + rb) = x4;
    }
}

// ---------------- k_final: full/att/maxatt _mpm — register accumulators, no shuffles ------
// grid = 3m * 2dir * 8b * 2sc = 96 blocks, 128 threads (thread = token s)
__global__ __launch_bounds__(128) void k_final(
    const float* __restrict__ vm, const float* __restrict__ vmT,
    const int* __restrict__ lasts, const float* __restrict__ attvT,
    const float* __restrict__ w_full, const float* __restrict__ w_att,
    const float* __restrict__ w_maxatt,
    float* __restrict__ out) {
    __shared__ float w2T[Hq * 20];   // [h][p]
    __shared__ float v2u[Hq];
    int blk = blockIdx.x;
    int m = blk >> 5;
    int rem = blk & 31;
    int dir = rem >> 4, b = (rem >> 1) & 7, sc = rem & 1;
    int t = threadIdx.x;
    const float* W = (m == 0) ? w_full : (m == 1) ? w_att : w_maxatt;
    for (int idx = t; idx < Pq * Hq; idx += 128) {
        int p = idx / Hq, h = idx - p * Hq;
        float w = W[idx];
        w2T[h * 20 + p] = w * w;
    }
    if (m == 0 && t < Hq) {
        int lastO = dir ? lasts[b] : lasts[Bq + b];
        v2u[t] = vm[(size_t)(1 - dir) * Bq * Sq * Hq + ((size_t)b * Sq + lastO) * Hq + t];
    }
    __syncthreads();

    int s = sc * 128 + t;
    const float* v1T = vmT + (size_t)(dir * Bq + b) * Hq * Sq;
    const float* v2T = attvT + ((size_t)(dir * 2 + (m == 2 ? 1 : 0)) * Bq + b) * Hq * Sq;

    float dotp[Pq], n1p[Pq], n2p[Pq];
#pragma unroll
    for (int p = 0; p < Pq; p++) { dotp[p] = 0.f; n1p[p] = 0.f; n2p[p] = 0.f; }
    float pd = 0.f, p1 = 0.f, p2 = 0.f;
    for (int h = 0; h < Hq; h++) {
        float v1 = v1T[h * Sq + s];
        float v2 = (m == 0) ? v2u[h] : v2T[h * Sq + s];
        float e1 = v1 * v2, e2 = v1 * v1, e3 = v2 * v2;
        pd += e1; p1 += e2; p2 += e3;
        const float4* wrow = (const float4*)(w2T + h * 20);
#pragma unroll
        for (int pq = 0; pq < 5; pq++) {
            float4 w4 = wrow[pq];
            dotp[pq * 4 + 0] += w4.x * e1; n1p[pq * 4 + 0] += w4.x * e2; n2p[pq * 4 + 0] += w4.x * e3;
            dotp[pq * 4 + 1] += w4.y * e1; n1p[pq * 4 + 1] += w4.y * e2; n2p[pq * 4 + 1] += w4.y * e3;
            dotp[pq * 4 + 2] += w4.z * e1; n1p[pq * 4 + 2] += w4.z * e2; n2p[pq * 4 + 2] += w4.z * e3;
            dotp[pq * 4 + 3] += w4.w * e1; n1p[pq * 4 + 3] += w4.w * e2; n2p[pq * 4 + 3] += w4.w * e3;
        }
    }
    int fbase = (m == 0) ? 2 : (m == 1) ? 63 : 84;
    float* orow = out + (size_t)dir * Bq * Sq * Fq + ((size_t)b * Sq + s) * Fq;
    orow[fbase] = pd / (fmaxf(sqrtf(p1), EPSq) * fmaxf(sqrtf(p2), EPSq));
#pragma unroll
    for (int p = 0; p < Pq; p++)
        orow[fbase + 1 + p] = dotp[p] / (fmaxf(sqrtf(n1p[p]), EPSq) * fmaxf(sqrtf(n2p[p]), EPSq));
}

extern "C" void kernel_launch(void* const* d_in, const int* in_sizes, int n_in,
                              void* d_out, int out_size, void* d_ws, size_t ws_size,
                              hipStream_t stream) {
    (void)in_sizes; (void)n_in; (void)out_size; (void)ws_size;
    const float* ctx_p    = (const float*)d_in[0];
    const int*   mask_p   = (const int*)d_in[1];
    const float* ctx_h    = (const float*)d_in[2];
    const int*   mask_h   = (const int*)d_in[3];
    const float* w_full   = (const float*)d_in[4];
    const float* w_maxpool= (const float*)d_in[5];
    const float* w_att    = (const float*)d_in[6];
    const float* w_maxatt = (const float*)d_in[7];
    float* out = (float*)d_out;
    float* ws = (float*)d_ws;

    const size_t BSH = (size_t)Bq * Sq * Hq;   // 204800
    const size_t BS  = (size_t)Bq * Sq;        // 2048
    const size_t BSS = (size_t)Bq * Sq * Sq;   // 524288
    const size_t BPS = (size_t)Bq * PPq * Sq;  // 43008

    float* vm     = ws;               ws += 2 * BSH;
    float* vmT    = ws;               ws += 2 * BSH;
    float* mf     = ws;               ws += 2 * BS;
    float* wn     = ws;               ws += 2 * BPS;
    float* cosm   = ws;               ws += BSS;
    float* cosT   = ws;               ws += BSS;
    unsigned* colmax = (unsigned*)ws; ws += BPS;
    float* colsum = ws;               ws += BPS;   // contiguous after colmax
    float* attvT  = ws;               ws += 4 * BSH;
    float* lens   = ws;               ws += 16;
    int*   lasts  = (int*)ws;         ws += 16;

    k_prep<<<16, 256, 0, stream>>>(ctx_p, mask_p, ctx_h, mask_h, w_maxpool,
                                   vm, vmT, mf, wn, lens, lasts, colmax);
    k_pw<<<Bq * PPq * 4, 256, 0, stream>>>(vmT, wn, mf, w_maxpool, lens,
                                           out, cosm, cosT, colmax, colsum);
    k_att<<<2 * Bq * 32, 256, 0, stream>>>(vm, mf, cosm, cosT, colmax, colsum, lens,
                                           out, attvT);
    k_final<<<96, 128, 0, stream>>>(vm, vmT, lasts, attvT, w_full, w_att, w_maxatt, out);
}

// Round 5
// 178.246 us; speedup vs baseline: 3.7957x; 1.0589x over previous
//
#include <hip/hip_runtime.h>

#define Bq 8
#define Sq 256
#define Hq 100
#define Pq 20
#define PPq 21
#define Fq 105
#define EPSq 1e-8f
#define NEGB -1e30f

__device__ __forceinline__ unsigned fkey(float f) {
    unsigned b = __float_as_uint(f);
    return (b & 0x80000000u) ? ~b : (b | 0x80000000u);
}
__device__ __forceinline__ float funkey(unsigned k) {
    return __uint_as_float((k & 0x80000000u) ? (k ^ 0x80000000u) : ~k);
}

// ---------------- k_prep: masks+lens, masked vm/vmT, 21 recip norms, zero col bufs --------
// grid = 16 blocks (side*8 + b), 256 threads (thread = token s)
__global__ __launch_bounds__(256) void k_prep(
    const float* __restrict__ ctx_p, const int* __restrict__ mask_p,
    const float* __restrict__ ctx_h, const int* __restrict__ mask_h,
    const float* __restrict__ w_mp,
    float* __restrict__ vm,   // [2][B][S][H]
    float* __restrict__ vmT,  // [2][B][H][S]
    float* __restrict__ mf,   // [2][B][S]
    float* __restrict__ wn,   // [2][B][PP][S] reciprocal norms (p=20 -> plain)
    float* __restrict__ lens, int* __restrict__ lasts,
    unsigned* __restrict__ colinit) {   // 2*B*PP*S words to zero
    __shared__ float tileT[Hq * 257];   // [h][s], pad stride 257
    __shared__ float w2T[Hq * 20];      // [h][p] = w^2
    __shared__ float smf[256];
    __shared__ int ired[256];
    int side = blockIdx.x >> 3;
    int b = blockIdx.x & 7;
    int t = threadIdx.x;

    for (int idx = blockIdx.x * 256 + t; idx < 2 * Bq * PPq * Sq; idx += 16 * 256)
        colinit[idx] = 0u;

    const float* ctx = side ? ctx_h : ctx_p;
    const int* mask = side ? mask_h : mask_p;
    int mi = mask[b * Sq + t];
    smf[t] = (float)mi;
    ired[t] = mi;
    for (int idx = t; idx < Pq * Hq; idx += 256) {
        int p = idx / Hq, h = idx - p * Hq;
        float w = w_mp[idx];
        w2T[h * 20 + p] = w * w;
    }
    __syncthreads();
    for (int o = 128; o; o >>= 1) {
        if (t < o) ired[t] += ired[t + o];
        __syncthreads();
    }
    if (t == 0) {
        int l = ired[0];
        lens[side * Bq + b] = (float)l;
        lasts[side * Bq + b] = l > 0 ? l - 1 : 0;
    }

    const float4* src = (const float4*)(ctx + (size_t)b * Sq * Hq);
    float4* vmo = (float4*)(vm + ((size_t)side * Bq + b) * Sq * Hq);
#pragma unroll
    for (int q = 0; q < 25; q++) {
        int F = t + 256 * q;
        int s = F / 25;
        int c = F - s * 25;
        float m = smf[s];
        float4 v4 = src[F];
        v4.x *= m; v4.y *= m; v4.z *= m; v4.w *= m;
        vmo[F] = v4;
        int h0 = c * 4;
        tileT[(h0 + 0) * 257 + s] = v4.x;
        tileT[(h0 + 1) * 257 + s] = v4.y;
        tileT[(h0 + 2) * 257 + s] = v4.z;
        tileT[(h0 + 3) * 257 + s] = v4.w;
    }
    __syncthreads();

    int s = t;
    float acc[PPq];
#pragma unroll
    for (int p = 0; p < PPq; p++) acc[p] = 0.f;
    float* vmTo = vmT + ((size_t)side * Bq + b) * Hq * Sq;
    for (int h = 0; h < Hq; h++) {
        float v = tileT[h * 257 + s];
        vmTo[h * Sq + s] = v;
        float e = v * v;
        acc[Pq] += e;
        const float4* wrow = (const float4*)(w2T + h * 20);
#pragma unroll
        for (int pq = 0; pq < 5; pq++) {
            float4 w4 = wrow[pq];
            acc[pq * 4 + 0] += w4.x * e;
            acc[pq * 4 + 1] += w4.y * e;
            acc[pq * 4 + 2] += w4.z * e;
            acc[pq * 4 + 3] += w4.w * e;
        }
    }
    float* wout = wn + ((size_t)side * Bq + b) * PPq * Sq;
#pragma unroll
    for (int p = 0; p < PPq; p++)
        wout[p * Sq + s] = 1.f / fmaxf(sqrtf(acc[p]), EPSq);
    mf[(size_t)side * Bq * Sq + b * Sq + s] = smf[s];
}

// ---------------- k_pw: num[p,i,j] once; row stats direct, col stats via atomics -----------
// grid = B*PP*8 blocks of 256; wave handles 8 i's, lane handles 4 j's.
__global__ __launch_bounds__(256) void k_pw(
    const float* __restrict__ vmT, const float* __restrict__ wn,
    const float* __restrict__ mf, const float* __restrict__ w_mp,
    const float* __restrict__ lens,
    float* __restrict__ out, float* __restrict__ cosm, float* __restrict__ cosT,
    unsigned* __restrict__ colmax, float* __restrict__ colsum) {
    __shared__ float cbmax[4][Sq];
    __shared__ float cbsum[4][Sq];
    int blk = blockIdx.x;
    int b = blk / (PPq * 8);
    int rem = blk - b * (PPq * 8);
    int p = rem >> 3, it = rem & 7;
    int t = threadIdx.x;
    int lane = t & 63;
    int wid = __builtin_amdgcn_readfirstlane(t >> 6);
    int i0 = it * 32 + wid * 8;

    const float* abase = vmT + (size_t)b * Hq * Sq;
    const float* bbase = vmT + (size_t)(Bq + b) * Hq * Sq;
    const float* wp = w_mp + (p < Pq ? p : 0) * Hq;

    float4 acc[8];
#pragma unroll
    for (int k = 0; k < 8; k++) acc[k] = make_float4(0.f, 0.f, 0.f, 0.f);

#pragma unroll 4
    for (int h = 0; h < Hq; h++) {
        float4 bq = ((const float4*)(bbase + h * Sq))[lane];
        float wl = wp[h];
        float wsc = (p < Pq) ? wl * wl : 1.0f;
        bq.x *= wsc; bq.y *= wsc; bq.z *= wsc; bq.w *= wsc;
        const float4* ap = (const float4*)(abase + h * Sq + i0);
        float4 a0 = ap[0], a1 = ap[1];
        float av[8] = {a0.x, a0.y, a0.z, a0.w, a1.x, a1.y, a1.z, a1.w};
#pragma unroll
        for (int k = 0; k < 8; k++) {
            acc[k].x += av[k] * bq.x; acc[k].y += av[k] * bq.y;
            acc[k].z += av[k] * bq.z; acc[k].w += av[k] * bq.w;
        }
    }

    const float* wn0 = wn + ((size_t)b * PPq + p) * Sq;
    const float* wn1 = wn + ((size_t)(Bq + b) * PPq + p) * Sq;
    float4 rn2 = ((const float4*)wn1)[lane];
    float4 mh4 = ((const float4*)(mf + (size_t)Bq * Sq + b * Sq))[lane];
    float invLh = 1.f / fmaxf(lens[Bq + b], EPSq);

    float cmax[4] = {NEGB, NEGB, NEGB, NEGB};
    float csum[4] = {0.f, 0.f, 0.f, 0.f};
#pragma unroll
    for (int k = 0; k < 8; k++) {
        float r1 = wn0[i0 + k];
        float4 v;
        v.x = acc[k].x * r1 * rn2.x;
        v.y = acc[k].y * r1 * rn2.y;
        v.z = acc[k].z * r1 * rn2.z;
        v.w = acc[k].w * r1 * rn2.w;
        float m0 = mh4.x > 0.5f ? v.x : NEGB;
        float m1 = mh4.y > 0.5f ? v.y : NEGB;
        float m2 = mh4.z > 0.5f ? v.z : NEGB;
        float m3 = mh4.w > 0.5f ? v.w : NEGB;
        float rmax = fmaxf(fmaxf(m0, m1), fmaxf(m2, m3));
        float rs = v.x + v.y + v.z + v.w;
        for (int o = 32; o; o >>= 1) {
            rmax = fmaxf(rmax, __shfl_xor(rmax, o, 64));
            rs += __shfl_xor(rs, o, 64);
        }
        if (lane == 0) {
            float* orow = out + ((size_t)(b * Sq + i0 + k)) * Fq;
            if (p < Pq) { orow[23 + p] = rmax; orow[43 + p] = rs * invLh; }
            else { orow[0] = rmax; orow[1] = rs * invLh; }
        }
        float mi = mf[b * Sq + i0 + k];
        if (mi > 0.5f) {
            cmax[0] = fmaxf(cmax[0], v.x); cmax[1] = fmaxf(cmax[1], v.y);
            cmax[2] = fmaxf(cmax[2], v.z); cmax[3] = fmaxf(cmax[3], v.w);
        }
        csum[0] += v.x; csum[1] += v.y; csum[2] += v.z; csum[3] += v.w;
        if (p == Pq) {
            ((float4*)(cosm + (size_t)(b * Sq + i0 + k) * Sq))[lane] = v;
            int jb = 4 * lane;
            cosT[((size_t)b * Sq + jb + 0) * Sq + i0 + k] = v.x;
            cosT[((size_t)b * Sq + jb + 1) * Sq + i0 + k] = v.y;
            cosT[((size_t)b * Sq + jb + 2) * Sq + i0 + k] = v.z;
            cosT[((size_t)b * Sq + jb + 3) * Sq + i0 + k] = v.w;
        }
    }
    ((float4*)&cbmax[wid][0])[lane] = make_float4(cmax[0], cmax[1], cmax[2], cmax[3]);
    ((float4*)&cbsum[wid][0])[lane] = make_float4(csum[0], csum[1], csum[2], csum[3]);
    __syncthreads();
    {
        int j = t;
        float mx = fmaxf(fmaxf(cbmax[0][j], cbmax[1][j]), fmaxf(cbmax[2][j], cbmax[3][j]));
        float sm = cbsum[0][j] + cbsum[1][j] + cbsum[2][j] + cbsum[3][j];
        size_t cidx = ((size_t)b * PPq + p) * Sq + j;
        atomicMax(colmax + cidx, fkey(mx));
        atomicAdd(colsum + cidx, sm);
    }
}

// ---------------- k_att: attention raw-sum & masked-max vectors (+ merged colfin) ---------
// grid = 2d*8b*32rt = 512 blocks, 256 threads: h = t&127, rh = t>>7 (4 r's each)
__global__ __launch_bounds__(256) void k_att(
    const float* __restrict__ vm, const float* __restrict__ mf,
    const float* __restrict__ cosm, const float* __restrict__ cosT,
    const unsigned* __restrict__ colmax, const float* __restrict__ colsum,
    const float* __restrict__ lens,
    float* __restrict__ out,
    float* __restrict__ attvT) {    // [2d*2j][B][H][S]
    __shared__ float L[Sq * 8];     // [k][8 r]
    __shared__ float bm[Sq];        // 0 valid / NEGB invalid
    int blk = blockIdx.x;
    int t = threadIdx.x;

    // merged column-stat fold (dir-1 rows), blocks 0..167
    if (blk < Bq * PPq) {
        int bcf = blk / PPq, pcf = blk - bcf * PPq;
        float mx = funkey(colmax[(size_t)blk * Sq + t]);
        float sm = colsum[(size_t)blk * Sq + t];
        float invLp = 1.f / fmaxf(lens[bcf], EPSq);
        float* orow = out + (size_t)Bq * Sq * Fq + (size_t)(bcf * Sq + t) * Fq;
        if (pcf < Pq) { orow[23 + pcf] = mx; orow[43 + pcf] = sm * invLp; }
        else { orow[0] = mx; orow[1] = sm * invLp; }
    }

    int d = blk >> 8;
    int rem = blk & 255;
    int b = rem >> 5, rt = rem & 31;
    int r0 = rt * 8;
    int h = t & 127, rh = t >> 7;

    const float* src = (d ? cosm : cosT) + (size_t)b * Sq * Sq;   // [k][r-cols]
#pragma unroll
    for (int q = 0; q < 2; q++) {
        int F = t + 256 * q;
        int k = F >> 1, c = F & 1;
        float4 v4 = *(const float4*)(src + (size_t)k * Sq + r0 + c * 4);
        *(float4*)(L + k * 8 + c * 4) = v4;
    }
    bm[t] = (mf[(size_t)(1 - d) * Bq * Sq + b * Sq + t] > 0.5f) ? 0.f : NEGB;
    __syncthreads();

    const float* vB = vm + (size_t)(1 - d) * Bq * Sq * Hq + (size_t)b * Sq * Hq + h;
    bool hv = (h < Hq);
    float am[4] = {0.f, 0.f, 0.f, 0.f};
    float ax[4] = {NEGB, NEGB, NEGB, NEGB};
#pragma unroll 16
    for (int k = 0; k < Sq; k++) {
        float v = hv ? vB[(size_t)k * Hq] : 0.f;
        float4 w = *(const float4*)(L + k * 8 + rh * 4);
        float bk = bm[k];
        float p0 = w.x * v, p1 = w.y * v, p2 = w.z * v, p3 = w.w * v;
        am[0] += p0; am[1] += p1; am[2] += p2; am[3] += p3;
        ax[0] = fmaxf(ax[0], p0 + bk); ax[1] = fmaxf(ax[1], p1 + bk);
        ax[2] = fmaxf(ax[2], p2 + bk); ax[3] = fmaxf(ax[3], p3 + bk);
    }
    if (hv) {
        int rb = r0 + rh * 4;
        float4 m4 = make_float4(am[0], am[1], am[2], am[3]);
        float4 x4 = make_float4(ax[0], ax[1], ax[2], ax[3]);
        *(float4*)(attvT + (((size_t)(d * 2 + 0) * Bq + b) * Hq + h) * Sq + rb) = m4;
        *(float4*)(attvT + (((size_t)(d * 2 + 1) * Bq + b) * Hq + h) * Sq + rb) = x4;
    }
}

// ---------------- k_final: full/att/maxatt _mpm — register accumulators, no shuffles ------
// grid = 3m * 2dir * 8b * 2sc = 96 blocks, 128 threads (thread = token s)
__global__ __launch_bounds__(128) void k_final(
    const float* __restrict__ vm, const float* __restrict__ vmT,
    const int* __restrict__ lasts, const float* __restrict__ attvT,
    const float* __restrict__ w_full, const float* __restrict__ w_att,
    const float* __restrict__ w_maxatt,
    float* __restrict__ out) {
    __shared__ float w2T[Hq * 20];   // [h][p]
    __shared__ float v2u[Hq];
    int blk = blockIdx.x;
    int m = blk >> 5;
    int rem = blk & 31;
    int dir = rem >> 4, b = (rem >> 1) & 7, sc = rem & 1;
    int t = threadIdx.x;
    const float* W = (m == 0) ? w_full : (m == 1) ? w_att : w_maxatt;
    for (int idx = t; idx < Pq * Hq; idx += 128) {
        int p = idx / Hq, h = idx - p * Hq;
        float w = W[idx];
        w2T[h * 20 + p] = w * w;
    }
    if (m == 0 && t < Hq) {
        int lastO = dir ? lasts[b] : lasts[Bq + b];
        v2u[t] = vm[(size_t)(1 - dir) * Bq * Sq * Hq + ((size_t)b * Sq + lastO) * Hq + t];
    }
    __syncthreads();

    int s = sc * 128 + t;
    const float* v1T = vmT + (size_t)(dir * Bq + b) * Hq * Sq;
    const float* v2T = attvT + ((size_t)(dir * 2 + (m == 2 ? 1 : 0)) * Bq + b) * Hq * Sq;

    float dotp[Pq], n1p[Pq], n2p[Pq];
#pragma unroll
    for (int p = 0; p < Pq; p++) { dotp[p] = 0.f; n1p[p] = 0.f; n2p[p] = 0.f; }
    float pd = 0.f, p1 = 0.f, p2 = 0.f;
#pragma unroll 2
    for (int h = 0; h < Hq; h++) {
        float v1 = v1T[h * Sq + s];
        float v2 = (m == 0) ? v2u[h] : v2T[h * Sq + s];
        float e1 = v1 * v2, e2 = v1 * v1, e3 = v2 * v2;
        pd += e1; p1 += e2; p2 += e3;
        const float4* wrow = (const float4*)(w2T + h * 20);
#pragma unroll
        for (int pq = 0; pq < 5; pq++) {
            float4 w4 = wrow[pq];
            dotp[pq * 4 + 0] += w4.x * e1; n1p[pq * 4 + 0] += w4.x * e2; n2p[pq * 4 + 0] += w4.x * e3;
            dotp[pq * 4 + 1] += w4.y * e1; n1p[pq * 4 + 1] += w4.y * e2; n2p[pq * 4 + 1] += w4.y * e3;
            dotp[pq * 4 + 2] += w4.z * e1; n1p[pq * 4 + 2] += w4.z * e2; n2p[pq * 4 + 2] += w4.z * e3;
            dotp[pq * 4 + 3] += w4.w * e1; n1p[pq * 4 + 3] += w4.w * e2; n2p[pq * 4 + 3] += w4.w * e3;
        }
    }
    int fbase = (m == 0) ? 2 : (m == 1) ? 63 : 84;
    float* orow = out + (size_t)dir * Bq * Sq * Fq + ((size_t)b * Sq + s) * Fq;
    orow[fbase] = pd / (fmaxf(sqrtf(p1), EPSq) * fmaxf(sqrtf(p2), EPSq));
#pragma unroll
    for (int p = 0; p < Pq; p++)
        orow[fbase + 1 + p] = dotp[p] / (fmaxf(sqrtf(n1p[p]), EPSq) * fmaxf(sqrtf(n2p[p]), EPSq));
}

extern "C" void kernel_launch(void* const* d_in, const int* in_sizes, int n_in,
                              void* d_out, int out_size, void* d_ws, size_t ws_size,
                              hipStream_t stream) {
    (void)in_sizes; (void)n_in; (void)out_size; (void)ws_size;
    const float* ctx_p    = (const float*)d_in[0];
    const int*   mask_p   = (const int*)d_in[1];
    const float* ctx_h    = (const float*)d_in[2];
    const int*   mask_h   = (const int*)d_in[3];
    const float* w_full   = (const float*)d_in[4];
    const float* w_maxpool= (const float*)d_in[5];
    const float* w_att    = (const float*)d_in[6];
    const float* w_maxatt = (const float*)d_in[7];
    float* out = (float*)d_out;
    float* ws = (float*)d_ws;

    const size_t BSH = (size_t)Bq * Sq * Hq;   // 204800
    const size_t BS  = (size_t)Bq * Sq;        // 2048
    const size_t BSS = (size_t)Bq * Sq * Sq;   // 524288
    const size_t BPS = (size_t)Bq * PPq * Sq;  // 43008

    float* vm     = ws;               ws += 2 * BSH;
    float* vmT    = ws;               ws += 2 * BSH;
    float* mf     = ws;               ws += 2 * BS;
    float* wn     = ws;               ws += 2 * BPS;
    float* cosm   = ws;               ws += BSS;
    float* cosT   = ws;               ws += BSS;
    unsigned* colmax = (unsigned*)ws; ws += BPS;
    float* colsum = ws;               ws += BPS;   // contiguous after colmax
    float* attvT  = ws;               ws += 4 * BSH;
    float* lens   = ws;               ws += 16;
    int*   lasts  = (int*)ws;         ws += 16;

    k_prep<<<16, 256, 0, stream>>>(ctx_p, mask_p, ctx_h, mask_h, w_maxpool,
                                   vm, vmT, mf, wn, lens, lasts, colmax);
    k_pw<<<Bq * PPq * 8, 256, 0, stream>>>(vmT, wn, mf, w_maxpool, lens,
                                           out, cosm, cosT, colmax, colsum);
    k_att<<<2 * Bq * 32, 256, 0, stream>>>(vm, mf, cosm, cosT, colmax, colsum, lens,
                                           out, attvT);
    k_final<<<96, 128, 0, stream>>>(vm, vmT, lasts, attvT, w_full, w_att, w_maxatt, out);
}